// Round 5
// baseline (95.755 us; speedup 1.0000x reference)
//
#include <hip/hip_runtime.h>
#include <hip/hip_bf16.h>

// Chamfer distance, p/q: (2, 64, 1024, 4) fp32; components 1..3.
// Kernel 1: grid = 128 batches x 2 sides x 16 m-chunks = 4096 one-wave blocks
//   (64 thr). 16 blocks/CU -> 4 waves/SIMD. Each wave: 1024 rows
//   (RPT=16/thread, stride-64) x 64 opposite points staged in LDS as
//   (-2x,-2y,-2z,qsq). Pair = 3 v_fma + 1 v_min. One broadcast ds_read_b128
//   feeds 64 lanes x 16 rows = 1024 pairs (64 VALU : 1 LDS instr, window
//   ~260 cyc per load with depth-2 prefetch -> LDS latency+bandwidth both
//   comfortably hidden; per-CU LDS demand 5.1us << 13.7us VALU floor).
//   Partial min (+ own norm) per (row, chunk) -> 16 MB workspace.
// Kernel 2: min over 16 chunks, clamp+eps+sqrt, block-reduce, atomicAdd.

#define TPB1 64
#define RPT 16         // rows per thread
#define SPLITS 16      // m-chunks per (batch,side)
#define CHUNK 64       // 1024 / SPLITS
#define RTPB 256
#define RBLOCKS 256

__global__ __launch_bounds__(TPB1, 4) void chamfer_min(
    const float4* __restrict__ P, const float4* __restrict__ Q,
    float* __restrict__ part)
{
    __shared__ float4 tile[CHUNK + 2];   // +2: prefetch overrun pad
    const int blk   = blockIdx.x;
    const int batch = blk >> 5;        // 0..127
    const int side  = (blk >> 4) & 1;  // 0: rows from P, opp Q; 1: swapped
    const int j     = blk & 15;        // m-chunk
    const int t     = threadIdx.x;     // 0..63
    const int base  = batch << 10;

    const float4* __restrict__ ownb = (side ? Q : P) + base;
    const float4* __restrict__ oppb = (side ? P : Q) + base;

    // Stage this wave's 64-point opposite chunk, -2 and norm folded in.
    {
        float4 v = oppb[(j << 6) + t];
        float qs = v.y * v.y + v.z * v.z + v.w * v.w;
        tile[t] = make_float4(-2.0f * v.y, -2.0f * v.z, -2.0f * v.w, qs);
    }

    float rx[RPT], ry[RPT], rz[RPT], acc[RPT];
#pragma unroll
    for (int r = 0; r < RPT; ++r) {
        float4 v = ownb[t + (r << 6)];     // rows t, t+64, ... (coalesced)
        rx[r] = v.y; ry[r] = v.z; rz[r] = v.w;
        acc[r] = 3.4e38f;
    }
    __syncthreads();   // single-wave block: compiles to a cheap waitcnt+barrier

    float4 a = tile[0];
    float4 b = tile[1];
    for (int m = 0; m < CHUNK; m += 2) {
        float4 n0 = tile[m + 2];           // prefetch (pad makes this safe)
#pragma unroll
        for (int r = 0; r < RPT; ++r) {
            float v = fmaf(a.x, rx[r], fmaf(a.y, ry[r], fmaf(a.z, rz[r], a.w)));
            acc[r] = fminf(acc[r], v);
        }
        float4 n1 = tile[m + 3];
#pragma unroll
        for (int r = 0; r < RPT; ++r) {
            float v = fmaf(b.x, rx[r], fmaf(b.y, ry[r], fmaf(b.z, rz[r], b.w)));
            acc[r] = fminf(acc[r], v);
        }
        a = n0; b = n1;
    }

    // part[blk*1024 + row] = min over this chunk (+ own norm)
    float* outp = part + (blk << 10);
#pragma unroll
    for (int r = 0; r < RPT; ++r) {
        float psq = rx[r] * rx[r] + ry[r] * ry[r] + rz[r] * rz[r];
        outp[t + (r << 6)] = acc[r] + psq;
    }
}

__global__ __launch_bounds__(RTPB) void chamfer_reduce(
    const float* __restrict__ part, float* __restrict__ out)
{
    __shared__ float ws[RTPB / 64];
    const int t = threadIdx.x;
    float sum = 0.0f;
    // 2 sides * 128 batches * 1024 rows = 2^18 row-slots
    for (int rid = blockIdx.x * RTPB + t; rid < (1 << 18); rid += RTPB * RBLOCKS) {
        const int bs  = rid >> 10;         // (batch*2+side), 0..255
        const int row = rid & 1023;
        const float* pp = part + (bs << 14) + row;
        float v = 3.4e38f;
#pragma unroll
        for (int k = 0; k < SPLITS; ++k) v = fminf(v, pp[k << 10]);
        sum += sqrtf(fmaxf(v, 0.0f) + 1e-12f);
    }
#pragma unroll
    for (int off = 32; off; off >>= 1) sum += __shfl_down(sum, off, 64);
    if ((t & 63) == 0) ws[t >> 6] = sum;
    __syncthreads();
    if (t == 0) atomicAdd(out, ws[0] + ws[1] + ws[2] + ws[3]);
}

extern "C" void kernel_launch(void* const* d_in, const int* in_sizes, int n_in,
                              void* d_out, int out_size, void* d_ws, size_t ws_size,
                              hipStream_t stream) {
    const float4* P = (const float4*)d_in[0];
    const float4* Q = (const float4*)d_in[1];
    float* out = (float*)d_out;
    float* part = (float*)d_ws;   // 4096 blocks * 1024 rows * 4 B = 16 MB

    hipMemsetAsync(d_out, 0, sizeof(float), stream);
    chamfer_min<<<dim3(128 * 2 * SPLITS), dim3(TPB1), 0, stream>>>(P, Q, part);
    chamfer_reduce<<<dim3(RBLOCKS), dim3(RTPB), 0, stream>>>(part, out);
}

// Round 6
// 85.845 us; speedup vs baseline: 1.1154x; 1.1154x over previous
//
#include <hip/hip_runtime.h>
#include <hip/hip_bf16.h>

// Chamfer distance, p/q: (2, 64, 1024, 4) fp32; components 1..3.
// Kernel 1 (R4 config + min3 pairing): grid = 128 x 2 x 8 m-chunks = 2048
//   blocks x 128 thr (8 blocks/CU -> 16 waves/CU). Each block: 1024 rows
//   (RPT=8, stride-128) x 128 opposite points staged in LDS as
//   (-2x,-2y,-2z,qsq). m-points processed in PAIRS: v0,v1 = 3 fma each,
//   acc = v_min3_f32(v0, v1, acc) -> 3.5 VALU ops/pair (was 4).
//   Unroll 4 m/iter, register prefetch 4 ahead (tile padded +4).
//   Partial min (+ own norm) per (row, chunk) -> 8 MB workspace.
// Kernel 2: float4 across rows: min over 8 chunks, clamp+eps+sqrt,
//   block-reduce, atomicAdd. Fully coalesced 16 B loads (~8 MB total).

#define TPB1 128
#define RPT 8          // rows per thread
#define SPLITS 8       // m-chunks per (batch,side)
#define CHUNK 128      // 1024 / SPLITS
#define RTPB 256
#define RBLOCKS 128

__device__ __forceinline__ float min3f(float a, float b, float c) {
    return __builtin_amdgcn_fmed3f(a, b, c) < fminf(a, fminf(b, c))
           ? fminf(a, fminf(b, c)) : fminf(a, fminf(b, c));
}

__global__ __launch_bounds__(TPB1, 4) void chamfer_min(
    const float4* __restrict__ P, const float4* __restrict__ Q,
    float* __restrict__ part)
{
    __shared__ float4 tile[CHUNK + 4];   // +4: prefetch overrun pad
    const int blk   = blockIdx.x;
    const int batch = blk >> 4;        // 0..127
    const int side  = (blk >> 3) & 1;  // 0: rows from P, opp Q; 1: swapped
    const int j     = blk & 7;         // m-chunk
    const int t     = threadIdx.x;
    const int base  = batch << 10;

    const float4* __restrict__ ownb = (side ? Q : P) + base;
    const float4* __restrict__ oppb = (side ? P : Q) + base;

    // Stage this block's 128-point opposite chunk, -2 and norm folded in.
    {
        float4 v = oppb[(j << 7) + t];
        float qs = v.y * v.y + v.z * v.z + v.w * v.w;
        tile[t] = make_float4(-2.0f * v.y, -2.0f * v.z, -2.0f * v.w, qs);
    }

    float rx[RPT], ry[RPT], rz[RPT], acc[RPT];
#pragma unroll
    for (int r = 0; r < RPT; ++r) {
        float4 v = ownb[t + (r << 7)];     // rows t, t+128, ... (coalesced)
        rx[r] = v.y; ry[r] = v.z; rz[r] = v.w;
        acc[r] = 3.4e38f;
    }
    __syncthreads();

    float4 a = tile[0], b = tile[1], c = tile[2], d = tile[3];
    for (int m = 0; m < CHUNK; m += 4) {
        float4 n0 = tile[m + 4];           // prefetch (pad makes this safe)
        float4 n1 = tile[m + 5];
#pragma unroll
        for (int r = 0; r < RPT; ++r) {
            float v0 = fmaf(a.x, rx[r], fmaf(a.y, ry[r], fmaf(a.z, rz[r], a.w)));
            float v1 = fmaf(b.x, rx[r], fmaf(b.y, ry[r], fmaf(b.z, rz[r], b.w)));
            // fmin(fmin(v0,v1),acc): compiler fuses to v_min3_f32
            acc[r] = fminf(fminf(v0, v1), acc[r]);
        }
        float4 n2 = tile[m + 6];
        float4 n3 = tile[m + 7];
#pragma unroll
        for (int r = 0; r < RPT; ++r) {
            float v2 = fmaf(c.x, rx[r], fmaf(c.y, ry[r], fmaf(c.z, rz[r], c.w)));
            float v3 = fmaf(d.x, rx[r], fmaf(d.y, ry[r], fmaf(d.z, rz[r], d.w)));
            acc[r] = fminf(fminf(v2, v3), acc[r]);
        }
        a = n0; b = n1; c = n2; d = n3;
    }

    // part[blk*1024 + row] = min over this chunk (+ own norm)
    float* outp = part + (blk << 10);
#pragma unroll
    for (int r = 0; r < RPT; ++r) {
        float psq = rx[r] * rx[r] + ry[r] * ry[r] + rz[r] * rz[r];
        outp[t + (r << 7)] = acc[r] + psq;
    }
}

__global__ __launch_bounds__(RTPB) void chamfer_reduce(
    const float* __restrict__ part, float* __restrict__ out)
{
    __shared__ float ws[RTPB / 64];
    const int t = threadIdx.x;
    float sum = 0.0f;
    // 2^18 rows as 2^16 float4 row-quads; layout part[bs][j][row], bs<256.
    for (int qid = blockIdx.x * RTPB + t; qid < (1 << 16); qid += RTPB * RBLOCKS) {
        const int bs = qid >> 8;           // (batch*2+side), 0..255
        const int q  = qid & 255;          // row-quad within batch-side
        const float4* pp = (const float4*)(part + (bs << 13)) + q;
        float4 v = pp[0];
#pragma unroll
        for (int k = 1; k < SPLITS; ++k) {
            float4 u = pp[k << 8];         // k*1024 floats = k*256 float4
            v.x = fminf(v.x, u.x); v.y = fminf(v.y, u.y);
            v.z = fminf(v.z, u.z); v.w = fminf(v.w, u.w);
        }
        sum += sqrtf(fmaxf(v.x, 0.0f) + 1e-12f) + sqrtf(fmaxf(v.y, 0.0f) + 1e-12f)
             + sqrtf(fmaxf(v.z, 0.0f) + 1e-12f) + sqrtf(fmaxf(v.w, 0.0f) + 1e-12f);
    }
#pragma unroll
    for (int off = 32; off; off >>= 1) sum += __shfl_down(sum, off, 64);
    if ((t & 63) == 0) ws[t >> 6] = sum;
    __syncthreads();
    if (t == 0) atomicAdd(out, ws[0] + ws[1] + ws[2] + ws[3]);
}

extern "C" void kernel_launch(void* const* d_in, const int* in_sizes, int n_in,
                              void* d_out, int out_size, void* d_ws, size_t ws_size,
                              hipStream_t stream) {
    const float4* P = (const float4*)d_in[0];
    const float4* Q = (const float4*)d_in[1];
    float* out = (float*)d_out;
    float* part = (float*)d_ws;   // 2048 blocks * 1024 rows * 4 B = 8 MB

    hipMemsetAsync(d_out, 0, sizeof(float), stream);
    chamfer_min<<<dim3(128 * 2 * SPLITS), dim3(TPB1), 0, stream>>>(P, Q, part);
    chamfer_reduce<<<dim3(RBLOCKS), dim3(RTPB), 0, stream>>>(part, out);
}